// Round 17
// baseline (7072.523 us; speedup 1.0000x reference)
//
#include <hip/hip_runtime.h>
#include <cstddef>
#include <cstdint>

#define HID   512
#define G4    2048   // 4*HID
#define NB    32     // batch
#define SEQL  1024
#define INPD  512
#define NBLK  128    // persistent blocks: block j owns hidden units [4j, 4j+4)
#define TPB   512

typedef _Float16 half8 __attribute__((ext_vector_type(8)));
typedef float    f32x4 __attribute__((ext_vector_type(4)));

__device__ __forceinline__ float sigm(float x) {
    return 1.0f / (1.0f + __expf(-x));
}
__device__ __forceinline__ float tanh_fast(float x) {
    float e = __expf(-2.0f * fabsf(x));
    float t = (1.0f - e) / (1.0f + e);
    return copysignf(t, x);
}

// p-major permuted gate index: g'' = j*16 + p, p = uu*4 + ty
// (uu = unit within block 0..3, ty = gate type). orig row = ty*HID + 4j + uu.
__device__ __forceinline__ int orig_gate(int gp) {
    int p = gp & 15, jj = gp >> 4;
    return (p & 3) * HID + jj * 4 + (p >> 2);
}

// ---- one-time: W_hh fp32 [2048][512] -> fp16, wh[j][p][k], p = uu*4 + ty
__global__ __launch_bounds__(256) void conv_whh(const float* __restrict__ whh,
                                                _Float16* __restrict__ wh) {
    int e = blockIdx.x * 256 + threadIdx.x;   // e < 2048*512
    int R = e >> 9, k = e & 511;
    int ty = R >> 9, rem = R & 511;
    int jj = rem >> 2, uu = rem & 3;
    int p = uu * 4 + ty;
    wh[((size_t)jj * 16 + p) * 512 + k] = (_Float16)whh[e];
}

// ---- one-time: h0 fp32 -> tagged u32 words (tag=0) into hbuf parity-0
__global__ __launch_bounds__(256) void conv_h0(const float* __restrict__ h0,
                                               unsigned* __restrict__ hb) {
    int e = blockIdx.x * 256 + threadIdx.x;   // e < NB*HID
    _Float16 hh = (_Float16)h0[e];
    unsigned short u;
    __builtin_memcpy(&u, &hh, 2);
    hb[e] = (unsigned)u;   // tag 0 in high 16 bits
}

// x_proj chunk GEMM with p-major PERMUTED output columns (unchanged)
__global__ __launch_bounds__(256) void xproj_gemm(const float* __restrict__ x,
                                                  const float* __restrict__ wih,
                                                  const float* __restrict__ bih,
                                                  const float* __restrict__ bhh,
                                                  float* __restrict__ xbuf,
                                                  int chunk, int SC) {
    __shared__ float As[16][68];
    __shared__ float Bs[16][68];
    const int m0 = blockIdx.x * 64;
    const int n0 = blockIdx.y * 64;
    const int tid = threadIdx.x;
    const int tx = tid % 16;
    const int ty = tid / 16;
    const int lr  = tid / 4;
    const int lc4 = tid % 4;

    float acc[4][4] = {};

    const int m = m0 + lr;
    const int b  = m / SC;
    const int tl = m % SC;
    const float* arow_base = x + ((size_t)b * SEQL + (size_t)chunk * SC + tl) * INPD + lc4 * 4;
    const float* brow_base = wih + (size_t)orig_gate(n0 + lr) * INPD + lc4 * 4;

    for (int k0 = 0; k0 < 512; k0 += 16) {
        float4 a4 = *(const float4*)(arow_base + k0);
        float4 b4 = *(const float4*)(brow_base + k0);
        As[lc4 * 4 + 0][lr] = a4.x;
        As[lc4 * 4 + 1][lr] = a4.y;
        As[lc4 * 4 + 2][lr] = a4.z;
        As[lc4 * 4 + 3][lr] = a4.w;
        Bs[lc4 * 4 + 0][lr] = b4.x;
        Bs[lc4 * 4 + 1][lr] = b4.y;
        Bs[lc4 * 4 + 2][lr] = b4.z;
        Bs[lc4 * 4 + 3][lr] = b4.w;
        __syncthreads();
        #pragma unroll
        for (int kk = 0; kk < 16; ++kk) {
            float4 av = *(const float4*)&As[kk][ty * 4];
            float4 bv = *(const float4*)&Bs[kk][tx * 4];
            float a[4] = {av.x, av.y, av.z, av.w};
            float bb[4] = {bv.x, bv.y, bv.z, bv.w};
            #pragma unroll
            for (int i = 0; i < 4; ++i)
                #pragma unroll
                for (int jj = 0; jj < 4; ++jj)
                    acc[i][jj] = fmaf(a[i], bb[jj], acc[i][jj]);
        }
        __syncthreads();
    }

    #pragma unroll
    for (int i = 0; i < 4; ++i) {
        int mo = m0 + ty * 4 + i;
        float* orow = xbuf + (size_t)mo * G4;
        #pragma unroll
        for (int jj = 0; jj < 4; ++jj) {
            int n = n0 + tx * 4 + jj;
            int og = orig_gate(n);
            orow[n] = acc[i][jj] + bih[og] + bhh[og];
        }
    }
}

// Persistent recurrence with SELF-VALIDATING TAGGED h exchange.
// hbuf: 2 parities x [NB][HID] u32 words, word = (tag<<16)|fp16(h).
// Step g consumes tag g from parity g&1; publishes tag g+1 to parity (g+1)&1.
// Stage = load tagged u64s, retry until all tags match -> the load IS the sync.
// No flags, no fences, no vmcnt drains. Double-buffer makes overwrite safe:
// a producer writes tag T+2 only after all blocks consumed tag T+1, by which
// time tag-T words (same parity) are dead.
// 128 blocks x 512 threads; block j owns units [4j,4j+4) = 16 gates (p-major).
// Compute: r14-verified 8-wave k-split MFMA + stride-67 part + fused reduce.
__global__ __launch_bounds__(512, 1)
void lstm_persist(const _Float16* __restrict__ wh,   // [NBLK][16][512] fp16
                  const float* __restrict__ xbuf,    // [NB*SC][G4] p-major perm
                  const float* __restrict__ c0,
                  unsigned long long* __restrict__ hbuf, // tagged [2][NB][HID/2] u64
                  float* __restrict__ cstate,        // [NB][HID]
                  float* __restrict__ out,           // [NB][SEQL][HID]
                  int step_base, int SC) {
    __shared__ __align__(16) _Float16 h_lds[32 * 520];   // [b][k], stride 520 halves
    __shared__ __align__(16) float    part[32 * 67];     // [(reg*8+w)][lane]

    const int j  = blockIdx.x;
    const int t  = threadIdx.x;
    const int u0 = 4 * j;

    // ---- MFMA role
    const int w    = t >> 6, lane = t & 63;
    const int mt   = w & 1, kg = w >> 1;
    const int arow = 16 * mt + (lane & 15);   // batch row (A)
    const int p_b  = lane & 15;               // gate row p (B)
    const int kl   = (lane >> 4) * 8;         // half sub-offset

    // ---- reduce role (t<64): b_r = t&31, unit pair pp = t>>5
    const int b_r = t & 31, pp = t >> 5;

    // ---- B fragment into registers, once (16 VGPRs; r14-proven resident)
    half8 wf[4];
    {
        const _Float16* wrow = wh + ((size_t)j * 16 + p_b) * 512 + kg * 128 + kl;
        #pragma unroll
        for (int q = 0; q < 4; ++q)
            wf[q] = *(const half8*)(wrow + q * 32);
    }

    // ---- cell state
    float cA = 0.0f, cB = 0.0f;
    if (t < 64) {
        const float* cs = (step_base == 0 ? c0 : cstate) + b_r * HID + u0 + 2 * pp;
        float2 cv = *(const float2*)cs;
        cA = cv.x; cB = cv.y;
    }

    for (int s = 0; s < SC; ++s) {
        const int g = step_base + s;

        // ---- xg prefetch: 8 contiguous gates = 2 float4 (wave 0)
        float4 x0 = {0,0,0,0}, x1 = {0,0,0,0};
        if (t < 64) {
            const float* xrow = xbuf + ((size_t)b_r * SC + s) * G4 + 16 * j + 8 * pp;
            x0 = *(const float4*)(xrow);
            x1 = *(const float4*)(xrow + 4);
        }

        // ---- stage h with tag-retry: 16 tagged u64 per thread (coalesced)
        const unsigned long long* hs8 = hbuf + (size_t)(g & 1) * 8192;
        const unsigned long long pat = ((unsigned long long)(unsigned)g << 48)
                                     | ((unsigned long long)(unsigned)g << 16);
        unsigned long long v[16];
        for (;;) {
            bool ok = true;
            #pragma unroll
            for (int q = 0; q < 16; ++q)
                v[q] = __hip_atomic_load(hs8 + q * 512 + t, __ATOMIC_RELAXED,
                                         __HIP_MEMORY_SCOPE_AGENT);
            #pragma unroll
            for (int q = 0; q < 16; ++q)
                ok &= ((v[q] & 0xFFFF0000FFFF0000ull) == pat);
            if (ok) break;
            __builtin_amdgcn_s_sleep(1);
        }
        // payload -> LDS (u32 = 2 fp16; conflict-free: consecutive t -> consec banks)
        #pragma unroll
        for (int q = 0; q < 16; ++q) {
            int j8 = q * 512 + t;                // tagged-u64 index
            int b  = j8 >> 8, r8 = j8 & 255;     // batch, unit-pair
            unsigned payload = (unsigned)(v[q] & 0xFFFF)
                             | (((unsigned)(v[q] >> 32) & 0xFFFFu) << 16);
            ((unsigned*)h_lds)[b * 260 + r8] = payload;
        }
        __syncthreads();   // sync1: h_lds complete (also guards part reuse)

        // ---- phase A: 4 MFMA per wave (A from LDS, B in VGPRs)
        f32x4 acc = {0.f, 0.f, 0.f, 0.f};
        #pragma unroll
        for (int q = 0; q < 4; ++q) {
            const int k = (kg * 4 + q) * 32 + kl;
            half8 av = *(const half8*)&h_lds[arow * 520 + k];
            acc = __builtin_amdgcn_mfma_f32_16x16x32_f16(av, wf[q], acc, 0, 0, 0);
        }
        // ---- partial C -> LDS (stride-67 planes, 2-way banks)
        #pragma unroll
        for (int r = 0; r < 4; ++r)
            part[(r * 8 + w) * 67 + lane] = acc[r];
        __syncthreads();   // sync2: part complete

        // ---- t<64: reduce 4 k-groups, cell update, tagged publish (no drain!)
        if (t < 64) {
            const int mtb   = b_r >> 4;
            const int row16 = b_r & 15;
            const int reg   = row16 & 3;
            const int lsA   = (row16 >> 2) * 16 + 8 * pp;
            float gs[8];
            #pragma unroll
            for (int e = 0; e < 8; ++e) {
                float sum = 0.0f;
                #pragma unroll
                for (int kgg = 0; kgg < 4; ++kgg)
                    sum += part[(reg * 8 + kgg * 2 + mtb) * 67 + lsA + e];
                gs[e] = sum;
            }
            float giA = gs[0] + x0.x, gfA = gs[1] + x0.y;
            float ggA = gs[2] + x0.z, goA = gs[3] + x0.w;
            float giB = gs[4] + x1.x, gfB = gs[5] + x1.y;
            float ggB = gs[6] + x1.z, goB = gs[7] + x1.w;
            cA = fmaf(sigm(gfA), cA, sigm(giA) * tanh_fast(ggA));
            float hA = sigm(goA) * tanh_fast(cA);
            cB = fmaf(sigm(gfB), cB, sigm(giB) * tanh_fast(ggB));
            float hB = sigm(goB) * tanh_fast(cB);

            _Float16 ha16 = (_Float16)hA, hb16 = (_Float16)hB;
            unsigned short hau, hbu;
            __builtin_memcpy(&hau, &ha16, 2);
            __builtin_memcpy(&hbu, &hb16, 2);
            const unsigned tg1 = (unsigned)(g + 1);
            unsigned long long pv = ((unsigned long long)((tg1 << 16) | hau))
                                  | ((unsigned long long)((tg1 << 16) | hbu) << 32);
            __hip_atomic_store(hbuf + (size_t)((g + 1) & 1) * 8192
                                    + b_r * 256 + 2 * j + pp,
                               pv, __ATOMIC_RELAXED, __HIP_MEMORY_SCOPE_AGENT);

            // out store (fp32): consumers don't depend on it
            float2 ov; ov.x = hA; ov.y = hB;
            *(float2*)&out[((size_t)b_r * SEQL + g) * HID + u0 + 2 * pp] = ov;
        }
        // no barrier here: h_lds(g+1) writes only race with part(g) reads by
        // wave 0, different buffers; part(g+1) writes wait on sync1(g+1).
    }

    if (t < 64) {
        float2 cv; cv.x = cA; cv.y = cB;
        *(float2*)&cstate[b_r * HID + u0 + 2 * pp] = cv;
    }
}

__global__ __launch_bounds__(256) void finalize(const unsigned* __restrict__ hfin,
                                                const float* __restrict__ cs,
                                                float* __restrict__ out) {
    int i = blockIdx.x * blockDim.x + threadIdx.x;
    size_t base = (size_t)NB * SEQL * HID;
    if (i < NB * HID) {
        unsigned short u = (unsigned short)(hfin[i] & 0xFFFF);
        _Float16 hh;
        __builtin_memcpy(&hh, &u, 2);
        out[base + i] = (float)hh;
        out[base + NB * HID + i] = cs[i];
    }
}

extern "C" void kernel_launch(void* const* d_in, const int* in_sizes, int n_in,
                              void* d_out, int out_size, void* d_ws, size_t ws_size,
                              hipStream_t stream) {
    const float* x   = (const float*)d_in[0];
    const float* h0  = (const float*)d_in[1];
    const float* c0  = (const float*)d_in[2];
    const float* wih = (const float*)d_in[3];
    const float* whh = (const float*)d_in[4];
    const float* bih = (const float*)d_in[5];
    const float* bhh = (const float*)d_in[6];
    float* out = (float*)d_out;

    char* ws = (char*)d_ws;
    unsigned long long* hbuf = (unsigned long long*)ws;            // 128 KB (2 parities)
    float*     cstate = (float*)(ws + 131072);                     // 64 KB
    _Float16*  wh_h   = (_Float16*)(ws + 131072 + 65536);          // 2 MB
    float*     xbuf   = (float*)(ws + 131072 + 65536 + 2097152);

    size_t fixed = 131072 + 65536 + 2097152;
    int SC = SEQL;
    while (SC > 64 && fixed + (size_t)NB * SC * G4 * sizeof(float) > ws_size) SC >>= 1;

    conv_whh<<<(2048 * 512) / 256, 256, 0, stream>>>(whh, wh_h);
    conv_h0<<<(NB * HID) / 256, 256, 0, stream>>>(h0, (unsigned*)hbuf);

    int nchunks = SEQL / SC;
    for (int ch = 0; ch < nchunks; ++ch) {
        dim3 grd(NB * SC / 64, G4 / 64);
        xproj_gemm<<<grd, 256, 0, stream>>>(x, wih, bih, bhh, xbuf, ch, SC);
        lstm_persist<<<NBLK, TPB, 0, stream>>>(wh_h, xbuf, c0, hbuf,
                                               cstate, out, ch * SC, SC);
    }

    // total steps = 1024 (even) -> final h tag 1024 lives in parity 0
    finalize<<<(NB * HID + 255) / 256, 256, 0, stream>>>((const unsigned*)hbuf,
                                                         cstate, out);
}

// Round 18
// 3224.420 us; speedup vs baseline: 2.1934x; 2.1934x over previous
//
#include <hip/hip_runtime.h>
#include <cstddef>
#include <cstdint>

#define HID   512
#define G4    2048   // 4*HID
#define NB    32     // batch
#define SEQL  1024
#define INPD  512
#define NBLK  128    // persistent blocks: block j owns hidden units [4j, 4j+4)
#define TPB   512

typedef _Float16 half8 __attribute__((ext_vector_type(8)));
typedef float    f32x4 __attribute__((ext_vector_type(4)));

__device__ __forceinline__ float sigm(float x) {
    return 1.0f / (1.0f + __expf(-x));
}
__device__ __forceinline__ float tanh_fast(float x) {
    float e = __expf(-2.0f * fabsf(x));
    float t = (1.0f - e) / (1.0f + e);
    return copysignf(t, x);
}

// Permuted gate index (type-major within block): g' = j*16 + ty*4 + uu
// orig W row for g': ty*HID + j*4 + uu.
__device__ __forceinline__ int orig_gate(int gp) {
    int r = gp & 15;
    return (r >> 2) * HID + (gp >> 4) * 4 + (r & 3);
}

// ---- one-time: W_hh fp32 [2048][512] -> fp16, per-block unit-major layout:
//      wh[j][p][k], p = uu*4 + ty  (B-operand rows for the persist MFMA)
__global__ __launch_bounds__(256) void conv_whh(const float* __restrict__ whh,
                                                _Float16* __restrict__ wh) {
    int e = blockIdx.x * 256 + threadIdx.x;   // e < 2048*512
    int R = e >> 9, k = e & 511;
    int ty = R >> 9, rem = R & 511;
    int j = rem >> 2, uu = rem & 3;
    int p = uu * 4 + ty;
    wh[((size_t)j * 16 + p) * 512 + k] = (_Float16)whh[e];
}

// ---- one-time: W_ih fp32 -> fp16 rows in xbuf-column (type-major g') order
__global__ __launch_bounds__(256) void conv_wih(const float* __restrict__ wih,
                                                _Float16* __restrict__ wi) {
    int e = blockIdx.x * 256 + threadIdx.x;   // e < 2048*512
    int R = e >> 9, k = e & 511;              // orig row R = ty*512 + u
    int ty = R >> 9, u = R & 511;
    int j = u >> 2, uu = u & 3;
    int gp = j * 16 + ty * 4 + uu;            // type-major permuted index
    wi[(size_t)gp * 512 + k] = (_Float16)wih[e];
}

// ---- one-time: permuted bias (bih+bhh)
__global__ __launch_bounds__(256) void conv_bias(const float* __restrict__ bih,
                                                 const float* __restrict__ bhh,
                                                 float* __restrict__ bp) {
    int gp = blockIdx.x * 256 + threadIdx.x;  // gp < 2048
    int og = orig_gate(gp);
    bp[gp] = bih[og] + bhh[og];
}

// ---- one-time: x fp32 -> fp16 (8 elems/thread)
__global__ __launch_bounds__(256) void conv_xh(const float* __restrict__ x,
                                               _Float16* __restrict__ xh) {
    int i = blockIdx.x * 256 + threadIdx.x;   // i < 32*1024*512/8
    const float4* s = (const float4*)(x + (size_t)i * 8);
    float4 a = s[0], b = s[1];
    half8 v = {(_Float16)a.x, (_Float16)a.y, (_Float16)a.z, (_Float16)a.w,
               (_Float16)b.x, (_Float16)b.y, (_Float16)b.z, (_Float16)b.w};
    *(half8*)(xh + (size_t)i * 8) = v;
}

// ---- xproj: fp16 MFMA GEMM, xbuf[m][g'] = x[row(m)]·wih[orig(g')] + bias[g']
// Tile 64(m)x64(n), 4 waves; wave w owns m-rows [16w,16w+16), 4 n-tiles.
// A/B staged in LDS (stride 36 halves: 16 distinct banks for 16 rows).
__global__ __launch_bounds__(256) void xproj_mfma(const _Float16* __restrict__ xh,
                                                  const _Float16* __restrict__ wi,
                                                  const float* __restrict__ bp,
                                                  float* __restrict__ xbuf,
                                                  int chunk, int SC) {
    __shared__ __align__(16) _Float16 As[64 * 36];
    __shared__ __align__(16) _Float16 Bs[64 * 36];

    const int m0 = blockIdx.x * 64;
    const int n0 = blockIdx.y * 64;
    const int t  = threadIdx.x;
    const int w  = t >> 6, lane = t & 63;

    // staging role: row r = t>>2 (0..63), k-quarter q4 = t&3 (8 halves each)
    const int sr = t >> 2, sq = (t & 3) * 8;
    const int m  = m0 + sr;
    const int b  = m / SC, tl = m % SC;
    const _Float16* arow = xh + ((size_t)b * SEQL + (size_t)chunk * SC + tl) * INPD + sq;
    const _Float16* brow = wi + (size_t)(n0 + sr) * 512 + sq;

    // MFMA role
    const int arow_l = 16 * w + (lane & 15);
    const int kl     = (lane >> 4) * 8;

    // bias for epilogue (4 n-tiles)
    float bias[4];
    #pragma unroll
    for (int nt = 0; nt < 4; ++nt)
        bias[nt] = bp[n0 + nt * 16 + (lane & 15)];

    f32x4 acc[4] = {};
    for (int kk = 0; kk < 16; ++kk) {
        *(half8*)&As[sr * 36 + sq] = *(const half8*)(arow + kk * 32);
        *(half8*)&Bs[sr * 36 + sq] = *(const half8*)(brow + kk * 32);
        __syncthreads();
        half8 av = *(const half8*)&As[arow_l * 36 + kl];
        #pragma unroll
        for (int nt = 0; nt < 4; ++nt) {
            half8 bv = *(const half8*)&Bs[(nt * 16 + (lane & 15)) * 36 + kl];
            acc[nt] = __builtin_amdgcn_mfma_f32_16x16x32_f16(av, bv, acc[nt], 0, 0, 0);
        }
        __syncthreads();
    }

    // epilogue: D col = lane&15 (n), row = (lane>>4)*4+reg (m)
    #pragma unroll
    for (int nt = 0; nt < 4; ++nt) {
        int n = n0 + nt * 16 + (lane & 15);
        #pragma unroll
        for (int reg = 0; reg < 4; ++reg) {
            int mg = m0 + 16 * w + (lane >> 4) * 4 + reg;
            xbuf[(size_t)mg * G4 + n] = acc[nt][reg] + bias[nt];
        }
    }
}

// Persistent recurrence — r12 structure EXACTLY, with stride-67 part planes.
// 128 blocks x 512 threads; block j owns units [4j,4j+4) = 16 gates.
// Per step: stage h -> LDS (16x8B LLC loads/thread); 4 MFMA/wave (B in VGPRs);
// part exchange (stride-67, 4 scalar stores); parallel reduce (512 threads,
// 1 output each) -> gl; phase B cell (t<64, 2 units); publish fp16; drain;
// flag; out store after arrive; own-flag poll + barrier.
__global__ __launch_bounds__(512, 1)
void lstm_persist(const _Float16* __restrict__ wh,   // [NBLK][16][512] fp16
                  const float* __restrict__ xbuf,    // [NB*SC][G4] permuted cols
                  const float* __restrict__ c0,
                  unsigned long long* __restrict__ hbuf, // fp16 [2][NB][HID] as u64
                  float* __restrict__ cstate,        // [NB][HID]
                  float* __restrict__ out,           // [NB][SEQL][HID]
                  int* __restrict__ flags,           // [NBLK*32]
                  int step_base, int SC) {
    __shared__ __align__(16) _Float16 h_lds[32 * 520];   // [b][k]
    __shared__ __align__(16) float    part[32 * 67];     // [(reg*8+w)][lane]
    __shared__ __align__(16) float    gl[32 * 20];       // [b][p]

    const int j  = blockIdx.x;
    const int t  = threadIdx.x;
    const int u0 = 4 * j;

    // ---- MFMA role
    const int w    = t >> 6, lane = t & 63;
    const int mt   = w & 1, kg = w >> 1;
    const int arow = 16 * mt + (lane & 15);   // batch row (A)
    const int p_b  = lane & 15;               // gate row p (B, unit-major)
    const int kl   = (lane >> 4) * 8;         // half sub-offset

    // ---- reduce role: thread t -> output (batch b_t, gate n_r)
    const int mt_r = t & 1;
    const int idx  = t >> 1;
    const int n_r  = idx & 15;
    const int m_r  = idx >> 4;                            // 0..15
    const int b_t  = 16 * mt_r + m_r;
    const int lsrc = (m_r >> 2) * 16 + n_r;               // source lane
    const int regr = m_r & 3;                             // source reg
    const int xcol = 16 * j + (n_r & 3) * 4 + (n_r >> 2); // p -> type-major col

    // ---- B fragment into registers, once (16 VGPRs)
    half8 wf[4];
    {
        const _Float16* wrow = wh + ((size_t)j * 16 + p_b) * 512 + kg * 128 + kl;
        #pragma unroll
        for (int q = 0; q < 4; ++q)
            wf[q] = *(const half8*)(wrow + q * 32);
    }

    // ---- cell state: thread t<64 owns batch b_c = t&31, units u0+2pp, +1
    float cA = 0.0f, cB = 0.0f;
    const int b_c = t & 31, pp = t >> 5;   // valid when t<64
    if (t < 64) {
        const float* cs = (step_base == 0 ? c0 : cstate) + b_c * HID + u0 + 2 * pp;
        float2 cv = *(const float2*)cs;
        cA = cv.x; cB = cv.y;
    }

    for (int s = 0; s < SC; ++s) {
        const int g = step_base + s;

        // prefetch this lane's xg
        float xg = xbuf[((size_t)b_t * SC + s) * G4 + xcol];

        // ---- stage h (32KB fp16) into LDS via LLC-coherent 8B loads
        const unsigned long long* hs8 = hbuf + (size_t)(g & 1) * 4096;
        #pragma unroll
        for (int i = 0; i < 4; ++i) {
            unsigned long long va = __hip_atomic_load(hs8 + i * 1024 + 2 * t,
                                                      __ATOMIC_RELAXED,
                                                      __HIP_MEMORY_SCOPE_AGENT);
            unsigned long long vb = __hip_atomic_load(hs8 + i * 1024 + 2 * t + 1,
                                                      __ATOMIC_RELAXED,
                                                      __HIP_MEMORY_SCOPE_AGENT);
            int j16 = i * 512 + t;                    // 16B unit index
            int br = j16 >> 6, k16 = j16 & 63;
            uint4 v;
            __builtin_memcpy(&v.x, &va, 8);
            __builtin_memcpy(&v.z, &vb, 8);
            *(uint4*)&h_lds[br * 520 + k16 * 8] = v;
        }
        __syncthreads();

        // ---- phase A: 4 MFMA per wave
        f32x4 acc = {0.f, 0.f, 0.f, 0.f};
        #pragma unroll
        for (int q = 0; q < 4; ++q) {
            const int k = (kg * 4 + q) * 32 + kl;
            half8 av = *(const half8*)&h_lds[arow * 520 + k];
            acc = __builtin_amdgcn_mfma_f32_16x16x32_f16(av, wf[q], acc, 0, 0, 0);
        }
        // stride-67 planes: 4 scalar stores (2-way banks) instead of b128
        #pragma unroll
        for (int r = 0; r < 4; ++r)
            part[(r * 8 + w) * 67 + lane] = acc[r];
        __syncthreads();

        // ---- reduce 4 k-group partials + xg -> gl[b][p]
        float sum = xg;
        #pragma unroll
        for (int kgg = 0; kgg < 4; ++kgg)
            sum += part[(regr * 8 + kgg * 2 + mt_r) * 67 + lsrc];
        gl[b_t * 20 + n_r] = sum;
        __syncthreads();

        // ---- phase B: cell update, 2 units per thread (t<64)
        float hA = 0.0f, hB = 0.0f;
        if (t < 64) {
            float4 gA = *(const float4*)&gl[b_c * 20 + 8 * pp];
            float4 gB = *(const float4*)&gl[b_c * 20 + 8 * pp + 4];
            cA = fmaf(sigm(gA.y), cA, sigm(gA.x) * tanh_fast(gA.z));
            hA = sigm(gA.w) * tanh_fast(cA);
            cB = fmaf(sigm(gB.y), cB, sigm(gB.x) * tanh_fast(gB.z));
            hB = sigm(gB.w) * tanh_fast(cB);

            _Float16 hv2[2] = {(_Float16)hA, (_Float16)hB};
            unsigned hu;
            __builtin_memcpy(&hu, hv2, 4);
            unsigned* hb32 = (unsigned*)hbuf;
            __hip_atomic_store(hb32 + (size_t)((g + 1) & 1) * 8192
                                    + b_c * 256 + (u0 >> 1) + pp,
                               hu, __ATOMIC_RELAXED, __HIP_MEMORY_SCOPE_AGENT);
        }
        __syncthreads();   // drains each wave's vmcnt => h stores acked at LLC

        // ---- arrive
        if (t == 0)
            __hip_atomic_store(&flags[j * 32], g + 1,
                               __ATOMIC_RELAXED, __HIP_MEMORY_SCOPE_AGENT);

        // ---- out store (fp32) AFTER arrive: HBM ack overlaps the poll
        if (t < 64) {
            float2 ov; ov.x = hA; ov.y = hB;
            *(float2*)&out[((size_t)b_c * SEQL + g) * HID + u0 + 2 * pp] = ov;
        }

        // ---- wait: thread t polls flag t
        if (t < NBLK) {
            while (__hip_atomic_load(&flags[t * 32], __ATOMIC_RELAXED,
                                     __HIP_MEMORY_SCOPE_AGENT) < g + 1)
                __builtin_amdgcn_s_sleep(1);
        }
        __syncthreads();
    }

    if (t < 64) {
        float2 cv; cv.x = cA; cv.y = cB;
        *(float2*)&cstate[b_c * HID + u0 + 2 * pp] = cv;
    }
}

__global__ __launch_bounds__(256) void finalize(const _Float16* __restrict__ hfin,
                                                const float* __restrict__ cs,
                                                float* __restrict__ out) {
    int i = blockIdx.x * blockDim.x + threadIdx.x;
    size_t base = (size_t)NB * SEQL * HID;
    if (i < NB * HID) {
        out[base + i] = (float)hfin[i];
        out[base + NB * HID + i] = cs[i];
    }
}

extern "C" void kernel_launch(void* const* d_in, const int* in_sizes, int n_in,
                              void* d_out, int out_size, void* d_ws, size_t ws_size,
                              hipStream_t stream) {
    const float* x   = (const float*)d_in[0];
    const float* h0  = (const float*)d_in[1];
    const float* c0  = (const float*)d_in[2];
    const float* wih = (const float*)d_in[3];
    const float* whh = (const float*)d_in[4];
    const float* bih = (const float*)d_in[5];
    const float* bhh = (const float*)d_in[6];
    float* out = (float*)d_out;

    char* ws = (char*)d_ws;
    size_t off = 0;
    int*       flags  = (int*)(ws + off);        off += 16384;                 // 16 KB
    _Float16*  hbuf_h = (_Float16*)(ws + off);   off += 65536;                 // 64 KB
    float*     cstate = (float*)(ws + off);      off += 65536;                 // 64 KB
    _Float16*  wh_h   = (_Float16*)(ws + off);   off += 2097152;               // 2 MB
    _Float16*  wi_h   = (_Float16*)(ws + off);   off += 2097152;               // 2 MB
    float*     biasp  = (float*)(ws + off);      off += 8192;                  // 8 KB
    _Float16*  xh     = (_Float16*)(ws + off);   off += (size_t)NB * SEQL * INPD * 2; // 32 MB
    float*     xbuf   = (float*)(ws + off);

    size_t fixed = off;
    int SC = SEQL;
    while (SC > 64 && fixed + (size_t)NB * SC * G4 * sizeof(float) > ws_size) SC >>= 1;

    hipMemsetAsync(flags, 0, 16384, stream);
    conv_whh<<<(2048 * 512) / 256, 256, 0, stream>>>(whh, wh_h);
    conv_wih<<<(2048 * 512) / 256, 256, 0, stream>>>(wih, wi_h);
    conv_bias<<<2048 / 256, 256, 0, stream>>>(bih, bhh, biasp);
    conv_xh<<<(NB * SEQL * INPD / 8) / 256, 256, 0, stream>>>(x, xh);
    // h0 -> fp16 hbuf parity 0 (reuse conv path inline via conv kernel)
    {
        // small dedicated conversion using conv_xh-style loop is overkill; do 1 kernel:
    }
    // conv h0
    conv_bias<<<1, 1, 0, stream>>>(bih, bhh, biasp); // no-op duplicate guard (cheap, deterministic)
    // real h0 conversion:
    {
        static_assert(NB * HID % 256 == 0, "");
    }
    // h0 fp32 -> fp16 into hbuf parity 0
    // (declared below main kernels)
    extern __global__ void conv_h0_k(const float*, _Float16*);
    conv_h0_k<<<(NB * HID) / 256, 256, 0, stream>>>(h0, hbuf_h);

    int nchunks = SEQL / SC;
    for (int ch = 0; ch < nchunks; ++ch) {
        dim3 grd(NB * SC / 64, G4 / 64);
        xproj_mfma<<<grd, 256, 0, stream>>>(xh, wi_h, biasp, xbuf, ch, SC);
        lstm_persist<<<NBLK, TPB, 0, stream>>>(wh_h, xbuf, c0,
                                               (unsigned long long*)hbuf_h,
                                               cstate, out, flags, ch * SC, SC);
    }

    // total steps = 1024 (even) -> final h parity is buffer 0
    finalize<<<(NB * HID + 255) / 256, 256, 0, stream>>>(hbuf_h, cstate, out);
}

// ---- h0 fp32 -> fp16 into hbuf buffer 0
__global__ __launch_bounds__(256) void conv_h0_k(const float* __restrict__ h0,
                                                 _Float16* __restrict__ hb) {
    int e = blockIdx.x * 256 + threadIdx.x;   // e < NB*HID
    hb[e] = (_Float16)h0[e];
}